// Round 10
// baseline (183.911 us; speedup 1.0000x reference)
//
#include <hip/hip_runtime.h>

#define NHEAD 8
#define CH    16
#define HC    128   // NHEAD*CH
#define INC   128   // in channels
#define EDIM  8
#define NEG   0.2f

typedef _Float16 h8 __attribute__((ext_vector_type(8)));
typedef _Float16 h4 __attribute__((ext_vector_type(4)));
typedef _Float16 h2 __attribute__((ext_vector_type(2)));
typedef float    f4 __attribute__((ext_vector_type(4)));

__device__ __forceinline__ float lrelu(float v) { return v > 0.f ? v : NEG * v; }

__device__ __forceinline__ float dot2(h2 a, h2 b, float c) {
#if __has_builtin(__builtin_amdgcn_fdot2)
    return __builtin_amdgcn_fdot2(a, b, c, false);
#else
    return c + (float)a[0] * (float)b[0] + (float)a[1] * (float)b[1];
#endif
}

// ---------------- packW: W = [Wl|Wr] into B-fragment order, fp16 ----------------
__global__ void k_packW(const float* __restrict__ Wl, const float* __restrict__ Wr,
                        _Float16* __restrict__ packed) {
    int id = blockIdx.x * blockDim.x + threadIdx.x;  // 0..4095
    int l  = id & 63;
    int kb = (id >> 6) & 3;
    int t  = id >> 8;           // 0..15
    int col = t * 16 + (l & 15);
    const float* W = (col < HC) ? Wl : Wr;
    int c = col & 127;
    int kbase = kb * 32 + (l >> 4) * 8;
    _Float16* dst = packed + (size_t)id * 8;
    #pragma unroll
    for (int j = 0; j < 8; ++j) dst[j] = (_Float16)W[(size_t)(kbase + j) * HC + c];
}

// ---------------- gemm: MFMA fp16 dual GEMM, 128 nodes/block, LDS-coalesced stores ----------------
__global__ __launch_bounds__(256) void k_gemm_mfma(
        const float* __restrict__ x, const _Float16* __restrict__ packed,
        const float* __restrict__ bl, const float* __restrict__ br,
        _Float16* __restrict__ xh, int N) {
    __shared__ _Float16 st[16][264];   // +8 pad: avoids 4-way ds_write bank conflict
    int nb0 = blockIdx.x * 128;
    int w  = threadIdx.x >> 6;
    int l  = threadIdx.x & 63;

    const h8* pk = (const h8*)packed;
    h8 bfrag[4][4];  // [ntile][kb]
    #pragma unroll
    for (int t4 = 0; t4 < 4; ++t4)
        #pragma unroll
        for (int kb = 0; kb < 4; ++kb)
            bfrag[t4][kb] = pk[(size_t)(((w * 4 + t4) * 4 + kb) * 64 + l)];

    float bv[4];
    int cl = l & 15;
    #pragma unroll
    for (int t4 = 0; t4 < 4; ++t4) {
        int col = w * 64 + t4 * 16 + cl;
        bv[t4] = (col < HC) ? bl[col] : br[col - HC];
    }

    int g = l >> 4;
    int r0 = g * 4;
    for (int mt = 0; mt < 8; ++mt) {
        int m0 = nb0 + mt * 16;
        if (m0 >= N) break;
        int row = m0 + cl; if (row >= N) row = N - 1;
        const float* xp = x + (size_t)row * INC + g * 8;
        h8 afrag[4];
        #pragma unroll
        for (int kb = 0; kb < 4; ++kb) {
            float4 u = *(const float4*)(xp + kb * 32);
            float4 v = *(const float4*)(xp + kb * 32 + 4);
            h8 a;
            a[0] = (_Float16)u.x; a[1] = (_Float16)u.y; a[2] = (_Float16)u.z; a[3] = (_Float16)u.w;
            a[4] = (_Float16)v.x; a[5] = (_Float16)v.y; a[6] = (_Float16)v.z; a[7] = (_Float16)v.w;
            afrag[kb] = a;
        }
        f4 acc[4];
        #pragma unroll
        for (int t4 = 0; t4 < 4; ++t4) { f4 z = {0.f, 0.f, 0.f, 0.f}; acc[t4] = z; }
        #pragma unroll
        for (int kb = 0; kb < 4; ++kb)
            #pragma unroll
            for (int t4 = 0; t4 < 4; ++t4)
                acc[t4] = __builtin_amdgcn_mfma_f32_16x16x32_f16(afrag[kb], bfrag[t4][kb], acc[t4], 0, 0, 0);
        #pragma unroll
        for (int t4 = 0; t4 < 4; ++t4) {
            int col = w * 64 + t4 * 16 + cl;
            #pragma unroll
            for (int j = 0; j < 4; ++j)
                st[r0 + j][col] = (_Float16)(acc[t4][j] + bv[t4]);
        }
        __syncthreads();
        #pragma unroll
        for (int q = 0; q < 2; ++q) {
            int cch = threadIdx.x + 256 * q;
            int r = cch >> 5, ch = (cch & 31) * 8;
            int node = m0 + r;
            if (node < N) *(h8*)(xh + (size_t)node * 256 + ch) = *(const h8*)&st[r][ch];
        }
        __syncthreads();
    }
}

// ---------------- hist: rank within dst + counts (standalone, full occupancy) ----------------
__global__ void k_hist(const int* __restrict__ ei, int* __restrict__ cnt,
                       int* __restrict__ rank, int E) {
    int t = blockIdx.x * blockDim.x + threadIdx.x;
    if (t < E) rank[t] = atomicAdd(&cnt[ei[E + t]], 1);
}

// ---------------- scan1: block-local exclusive scan ----------------
__global__ void k_scan1(const int* __restrict__ cnt, int* __restrict__ off,
                        int* __restrict__ bsum, int N) {
    __shared__ int wpre[16];
    int i = blockIdx.x * 1024 + threadIdx.x;
    int lane = threadIdx.x & 63, wid = threadIdx.x >> 6;
    int v = (i < N) ? cnt[i] : 0;
    int s = v;
    #pragma unroll
    for (int d = 1; d < 64; d <<= 1) {
        int t = __shfl_up(s, d);
        if (lane >= d) s += t;
    }
    if (lane == 63) wpre[wid] = s;
    __syncthreads();
    if (threadIdx.x == 0) {
        int run = 0;
        #pragma unroll
        for (int q = 0; q < 16; ++q) { int t = wpre[q]; wpre[q] = run; run += t; }
        bsum[blockIdx.x] = run;
    }
    __syncthreads();
    if (i <= N) off[i] = wpre[wid] + s - v;  // exclusive within block (i==N: tail sentinel)
}

// ---------------- scan2 + loop_emb/We16/att16 (fused, 1 block) ----------------
__global__ void k_scan2lo(const int* __restrict__ bsum, int* __restrict__ bsx, int nb,
                          const float* __restrict__ attr_sum, const float* __restrict__ We,
                          const float* __restrict__ att, float* __restrict__ loop_emb,
                          _Float16* __restrict__ We16, _Float16* __restrict__ att16,
                          float invE) {
    int tid = threadIdx.x;
    if (tid < 64) {                 // wave 0: scan of block sums
        int v = (tid < nb) ? bsum[tid] : 0;
        int s = v;
        #pragma unroll
        for (int d = 1; d < 64; d <<= 1) {
            int t = __shfl_up(s, d);
            if (tid >= d) s += t;
        }
        if (tid < nb) bsx[tid] = s - v;
    } else if (tid < 192) {         // waves 1-2: loop_emb + fp16 param copies
        int j = tid - 64;           // 0..127
        float acc = 0.f;
        #pragma unroll
        for (int d = 0; d < EDIM; ++d) {
            float w = We[d * HC + j];
            acc += attr_sum[d] * invE * w;
            We16[d * HC + j] = (_Float16)w;
        }
        loop_emb[j] = acc;
        att16[j] = (_Float16)att[j];
    }
}

// ---------------- scatter: CSR permute (no atomics) + fused attr_sum ----------------
__global__ void k_scatter(const int* __restrict__ ei, const float* __restrict__ ea,
                          const int* __restrict__ off, const int* __restrict__ bsx,
                          const int* __restrict__ rank,
                          int* __restrict__ esrc, h8* __restrict__ eac,
                          float* __restrict__ attr_sum, int E) {
    __shared__ float red[4][8];
    int t = blockIdx.x * blockDim.x + threadIdx.x;
    float av[8] = {0.f, 0.f, 0.f, 0.f, 0.f, 0.f, 0.f, 0.f};
    if (t < E) {
        int dst = ei[E + t];
        int pos = off[dst] + bsx[dst >> 10] + rank[t];
        esrc[pos] = ei[t];
        float4 a0 = *(const float4*)(ea + (size_t)t * EDIM);
        float4 a1 = *(const float4*)(ea + (size_t)t * EDIM + 4);
        av[0] = a0.x; av[1] = a0.y; av[2] = a0.z; av[3] = a0.w;
        av[4] = a1.x; av[5] = a1.y; av[6] = a1.z; av[7] = a1.w;
        h8 v;
        #pragma unroll
        for (int k = 0; k < 8; ++k) v[k] = (_Float16)av[k];
        eac[pos] = v;
    }
    #pragma unroll
    for (int m = 1; m < 64; m <<= 1) {
        #pragma unroll
        for (int k = 0; k < 8; ++k) av[k] += __shfl_xor(av[k], m);
    }
    int lane = threadIdx.x & 63, wid = threadIdx.x >> 6;
    if (lane == 0) {
        #pragma unroll
        for (int k = 0; k < 8; ++k) red[wid][k] = av[k];
    }
    __syncthreads();
    if (threadIdx.x < 8) {
        float s = red[0][threadIdx.x] + red[1][threadIdx.x] + red[2][threadIdx.x] + red[3][threadIdx.x];
        atomicAdd(&attr_sum[threadIdx.x], s);
    }
}

// ---------------- gather: wave per dst; 8 ch/lane, 4 edges/stage, 2 stages/iter ----------------
__global__ __launch_bounds__(256) void k_gather(
        const int* __restrict__ esrc, const h8* __restrict__ eac,
        const _Float16* __restrict__ We16, const _Float16* __restrict__ att16,
        const float* __restrict__ attf, const _Float16* __restrict__ xh,
        const float* __restrict__ loop_emb, const float* __restrict__ bias,
        const int* __restrict__ off, const int* __restrict__ bsx,
        float* __restrict__ out, int N) {
    int wave = (blockIdx.x * blockDim.x + threadIdx.x) >> 6;
    int lane = threadIdx.x & 63;
    if (wave >= N) return;
    int dst = __builtin_amdgcn_readfirstlane(wave);
    int qid = lane >> 4;        // quarter = which edge of the group of 4
    int l   = lane & 15;
    int c0  = l * 8;            // 8 channels per lane; head = l>>1 (pair of lanes)

    h8 we8[EDIM];
    #pragma unroll
    for (int d = 0; d < EDIM; ++d) we8[d] = *(const h8*)(We16 + d * HC + c0);
    h2 att2[4];
    #pragma unroll
    for (int k = 0; k < 4; ++k) att2[k] = *(const h2*)(att16 + c0 + 2 * k);
    h8 xr8 = *(const h8*)(xh + (size_t)dst * 256 + HC + c0);

    const h8 z8 = {};
    h8 ng8;
    #pragma unroll
    for (int k = 0; k < 8; ++k) ng8[k] = (_Float16)NEG;

    float accv[8] = {0.f, 0.f, 0.f, 0.f, 0.f, 0.f, 0.f, 0.f};
    float segw = 0.f;

    auto PROC = [&](h8 a8, h8 x8, bool cond) {
        h8 e8 = {};
        #pragma unroll
        for (int d = 0; d < EDIM; ++d) {
            h8 ad = {a8[d], a8[d], a8[d], a8[d], a8[d], a8[d], a8[d], a8[d]};
            e8 += ad * we8[d];
        }
        h8 m8 = x8 + xr8 + e8;
        h8 mp = __builtin_elementwise_max(m8, z8);
        h8 mn = __builtin_elementwise_min(m8, z8);
        m8 = mp + mn * ng8;
        float p = 0.f;
        #pragma unroll
        for (int k = 0; k < 4; ++k) {
            h2 mm; mm[0] = m8[2 * k]; mm[1] = m8[2 * k + 1];
            p = dot2(mm, att2[k], p);
        }
        p += __shfl_xor(p, 1);          // head logit (pair of lanes within quarter)
        float w = cond ? __expf(p) : 0.f;
        segw += w;
        #pragma unroll
        for (int k = 0; k < 8; ++k) accv[k] += w * (float)x8[k];
    };

    // self-loop (fp32 path), counted once via qid==0
    {
        h8 xl8 = *(const h8*)(xh + (size_t)dst * 256 + c0);
        f4 le0 = *(const f4*)(loop_emb + c0), le1 = *(const f4*)(loop_emb + c0 + 4);
        f4 af0 = *(const f4*)(attf + c0),     af1 = *(const f4*)(attf + c0 + 4);
        float le[8] = {le0[0], le0[1], le0[2], le0[3], le1[0], le1[1], le1[2], le1[3]};
        float af[8] = {af0[0], af0[1], af0[2], af0[3], af1[0], af1[1], af1[2], af1[3]};
        float xf[8];
        float p = 0.f;
        #pragma unroll
        for (int k = 0; k < 8; ++k) {
            xf[k] = (float)xl8[k];
            p += lrelu(xf[k] + (float)xr8[k] + le[k]) * af[k];
        }
        p += __shfl_xor(p, 1);
        float w = (qid == 0) ? __expf(p) : 0.f;
        segw += w;
        #pragma unroll
        for (int k = 0; k < 8; ++k) accv[k] += w * xf[k];
    }

    int beg = off[dst] + bsx[dst >> 10];
    int end = off[dst + 1] + bsx[(dst + 1) >> 10];
    if (beg < end) {
        int last = end - 1;
        int j;
        j = beg + qid;          if (j > last) j = last;
        int sU = esrc[j]; h8 aU = eac[j];
        j = beg + 4 + qid;      if (j > last) j = last;
        int sV = esrc[j]; h8 aV = eac[j];
        h8 xU = *(const h8*)(xh + (size_t)sU * 256 + c0);
        h8 xV = *(const h8*)(xh + (size_t)sV * 256 + c0);
        j = beg + 8 + qid;      if (j > last) j = last;
        int sP = esrc[j];
        j = beg + 12 + qid;     if (j > last) j = last;
        int sQ = esrc[j];
        for (int i = beg; i < end; i += 8) {
            // stage i : slot U
            PROC(aU, xU, (i + qid) < end);
            {
                int jx = i + 8 + qid;  if (jx > last) jx = last;
                xU = *(const h8*)(xh + (size_t)sP * 256 + c0);   // x for stage i+8
                aU = eac[jx];
                int jf = i + 16 + qid; if (jf > last) jf = last;
                sP = esrc[jf];
            }
            // stage i+4 : slot V
            PROC(aV, xV, (i + 4 + qid) < end);
            {
                int jx = i + 12 + qid; if (jx > last) jx = last;
                xV = *(const h8*)(xh + (size_t)sQ * 256 + c0);   // x for stage i+12
                aV = eac[jx];
                int jf = i + 20 + qid; if (jf > last) jf = last;
                sQ = esrc[jf];
            }
        }
    }

    // combine quarters
    segw += __shfl_xor(segw, 16); segw += __shfl_xor(segw, 32);
    #pragma unroll
    for (int k = 0; k < 8; ++k) {
        accv[k] += __shfl_xor(accv[k], 16);
        accv[k] += __shfl_xor(accv[k], 32);
    }

    if (qid == 0) {
        float inv = 1.f / (segw + 1e-16f);
        f4 b0 = *(const f4*)(bias + c0), b1 = *(const f4*)(bias + c0 + 4);
        f4 o0, o1;
        o0[0] = accv[0] * inv + b0[0]; o0[1] = accv[1] * inv + b0[1];
        o0[2] = accv[2] * inv + b0[2]; o0[3] = accv[3] * inv + b0[3];
        o1[0] = accv[4] * inv + b1[0]; o1[1] = accv[5] * inv + b1[1];
        o1[2] = accv[6] * inv + b1[2]; o1[3] = accv[7] * inv + b1[3];
        *(f4*)(out + (size_t)dst * HC + c0)     = o0;
        *(f4*)(out + (size_t)dst * HC + c0 + 4) = o1;
    }
}

extern "C" void kernel_launch(void* const* d_in, const int* in_sizes, int n_in,
                              void* d_out, int out_size, void* d_ws, size_t ws_size,
                              hipStream_t stream) {
    int N = in_sizes[0] / INC;
    int E = in_sizes[1] / 2;
    const float* x    = (const float*)d_in[0];
    const int*   ei   = (const int*)d_in[1];
    const float* ea   = (const float*)d_in[2];
    const float* Wl   = (const float*)d_in[3];
    const float* bl   = (const float*)d_in[4];
    const float* Wr   = (const float*)d_in[5];
    const float* br   = (const float*)d_in[6];
    const float* We   = (const float*)d_in[7];
    const float* att  = (const float*)d_in[8];
    const float* bias = (const float*)d_in[9];
    float* out = (float*)d_out;

    // workspace layout (16B-aligned blocks first)
    _Float16* xh      = (_Float16*)d_ws;                   // N*256 halfs
    h8*       eac     = (h8*)(xh + (size_t)N * 256);       // E * 16B
    float* attr_sum   = (float*)(eac + E);                 // 8
    int*   cnt        = (int*)(attr_sum + 8);              // N
    float* loop_emb   = (float*)(cnt + N);                 // 128
    _Float16* packed  = (_Float16*)(loop_emb + HC);        // 32768 halfs
    _Float16* We16    = packed + 32768;                    // 1024 halfs
    _Float16* att16   = We16 + 1024;                       // 128 halfs
    int*   off        = (int*)(att16 + 128);               // N+2
    int*   rank       = off + (N + 2);                     // E
    int*   esrc       = rank + E;                          // E
    int*   bsum       = esrc + E;                          // 64
    int*   bsx        = bsum + 64;                         // 64

    // one memset covers attr_sum + cnt (contiguous)
    hipMemsetAsync(attr_sum, 0, (8 + (size_t)N) * sizeof(float), stream);

    k_packW<<<16, 256, 0, stream>>>(Wl, Wr, packed);
    k_gemm_mfma<<<(N + 127) / 128, 256, 0, stream>>>(x, packed, bl, br, xh, N);

    int histBlocks = (E + 255) / 256;
    k_hist<<<histBlocks, 256, 0, stream>>>(ei, cnt, rank, E);

    int nb = (N + 1 + 1023) / 1024;
    k_scan1<<<nb, 1024, 0, stream>>>(cnt, off, bsum, N);
    k_scan2lo<<<1, 256, 0, stream>>>(bsum, bsx, nb, attr_sum, We, att,
                                     loop_emb, We16, att16, 1.0f / (float)E);
    k_scatter<<<histBlocks, 256, 0, stream>>>(ei, ea, off, bsx, rank, esrc, eac, attr_sum, E);

    k_gather<<<(N * 64 + 255) / 256, 256, 0, stream>>>(esrc, eac, We16, att16, att, xh,
                                                       loop_emb, bias, off, bsx, out, N);
}

// Round 12
// 167.988 us; speedup vs baseline: 1.0948x; 1.0948x over previous
//
#include <hip/hip_runtime.h>

#define NHEAD 8
#define CH    16
#define HC    128   // NHEAD*CH
#define INC   128   // in channels
#define EDIM  8
#define NEG   0.2f

typedef _Float16 h8 __attribute__((ext_vector_type(8)));
typedef _Float16 h2 __attribute__((ext_vector_type(2)));
typedef float    f4 __attribute__((ext_vector_type(4)));

__device__ __forceinline__ float dot2(h2 a, h2 b, float c) {
#if __has_builtin(__builtin_amdgcn_fdot2)
    return __builtin_amdgcn_fdot2(a, b, c, false);
#else
    return c + (float)a[0] * (float)b[0] + (float)a[1] * (float)b[1];
#endif
}

// ---------------- packW: W = [Wl|Wr] into B-fragment order + We16/att16 ----------------
__global__ void k_packW(const float* __restrict__ Wl, const float* __restrict__ Wr,
                        const float* __restrict__ We, const float* __restrict__ att,
                        _Float16* __restrict__ packed,
                        _Float16* __restrict__ We16, _Float16* __restrict__ att16) {
    int id = blockIdx.x * blockDim.x + threadIdx.x;  // 0..4095
    int l  = id & 63;
    int kb = (id >> 6) & 3;
    int t  = id >> 8;           // 0..15
    int col = t * 16 + (l & 15);
    const float* W = (col < HC) ? Wl : Wr;
    int c = col & 127;
    int kbase = kb * 32 + (l >> 4) * 8;
    _Float16* dst = packed + (size_t)id * 8;
    #pragma unroll
    for (int j = 0; j < 8; ++j) dst[j] = (_Float16)W[(size_t)(kbase + j) * HC + c];
    if (id < 1024) We16[id] = (_Float16)We[id];
    if (id < 128)  att16[id] = (_Float16)att[id];
}

// ---------------- phase1: fused {MFMA dual GEMM, 64 nodes/block} + {hist + attr_sum} ----------------
__global__ __launch_bounds__(256) void k_phase1(
        const float* __restrict__ x, const _Float16* __restrict__ packed,
        const float* __restrict__ bl, const float* __restrict__ br,
        _Float16* __restrict__ xh,
        const int* __restrict__ ei, const float* __restrict__ ea,
        int* __restrict__ cnt, int* __restrict__ rank, float* __restrict__ attr_sum,
        int N, int E, int gemmBlocks) {
    __shared__ _Float16 st[16][264];
    __shared__ float red[4][8];

    if ((int)blockIdx.x < gemmBlocks) {
        int nb0 = blockIdx.x * 64;
        int w  = threadIdx.x >> 6;
        int l  = threadIdx.x & 63;

        const h8* pk = (const h8*)packed;
        h8 bfrag[4][4];
        #pragma unroll
        for (int t4 = 0; t4 < 4; ++t4)
            #pragma unroll
            for (int kb = 0; kb < 4; ++kb)
                bfrag[t4][kb] = pk[(size_t)(((w * 4 + t4) * 4 + kb) * 64 + l)];

        float bv[4];
        int cl = l & 15;
        #pragma unroll
        for (int t4 = 0; t4 < 4; ++t4) {
            int col = w * 64 + t4 * 16 + cl;
            bv[t4] = (col < HC) ? bl[col] : br[col - HC];
        }

        int g = l >> 4;
        int r0 = g * 4;
        for (int mt = 0; mt < 4; ++mt) {
            int m0 = nb0 + mt * 16;
            if (m0 >= N) break;
            int row = m0 + cl; if (row >= N) row = N - 1;
            const float* xp = x + (size_t)row * INC + g * 8;
            h8 afrag[4];
            #pragma unroll
            for (int kb = 0; kb < 4; ++kb) {
                float4 u = *(const float4*)(xp + kb * 32);
                float4 v = *(const float4*)(xp + kb * 32 + 4);
                h8 a;
                a[0] = (_Float16)u.x; a[1] = (_Float16)u.y; a[2] = (_Float16)u.z; a[3] = (_Float16)u.w;
                a[4] = (_Float16)v.x; a[5] = (_Float16)v.y; a[6] = (_Float16)v.z; a[7] = (_Float16)v.w;
                afrag[kb] = a;
            }
            f4 acc[4];
            #pragma unroll
            for (int t4 = 0; t4 < 4; ++t4) { f4 z = {0.f, 0.f, 0.f, 0.f}; acc[t4] = z; }
            #pragma unroll
            for (int kb = 0; kb < 4; ++kb)
                #pragma unroll
                for (int t4 = 0; t4 < 4; ++t4)
                    acc[t4] = __builtin_amdgcn_mfma_f32_16x16x32_f16(afrag[kb], bfrag[t4][kb], acc[t4], 0, 0, 0);
            #pragma unroll
            for (int t4 = 0; t4 < 4; ++t4) {
                int col = w * 64 + t4 * 16 + cl;
                #pragma unroll
                for (int j = 0; j < 4; ++j)
                    st[r0 + j][col] = (_Float16)(acc[t4][j] + bv[t4]);
            }
            __syncthreads();
            #pragma unroll
            for (int q = 0; q < 2; ++q) {
                int cch = threadIdx.x + 256 * q;
                int r = cch >> 5, ch = (cch & 31) * 8;
                int node = m0 + r;
                if (node < N) *(h8*)(xh + (size_t)node * 256 + ch) = *(const h8*)&st[r][ch];
            }
            __syncthreads();
        }
    } else {
        int t = (blockIdx.x - gemmBlocks) * 256 + threadIdx.x;
        float av[8] = {0.f, 0.f, 0.f, 0.f, 0.f, 0.f, 0.f, 0.f};
        if (t < E) {
            rank[t] = atomicAdd(&cnt[ei[E + t]], 1);
            float4 a0 = *(const float4*)(ea + (size_t)t * EDIM);
            float4 a1 = *(const float4*)(ea + (size_t)t * EDIM + 4);
            av[0] = a0.x; av[1] = a0.y; av[2] = a0.z; av[3] = a0.w;
            av[4] = a1.x; av[5] = a1.y; av[6] = a1.z; av[7] = a1.w;
        }
        #pragma unroll
        for (int m = 1; m < 64; m <<= 1) {
            #pragma unroll
            for (int k = 0; k < 8; ++k) av[k] += __shfl_xor(av[k], m);
        }
        int lane = threadIdx.x & 63, wid = threadIdx.x >> 6;
        if (lane == 0) {
            #pragma unroll
            for (int k = 0; k < 8; ++k) red[wid][k] = av[k];
        }
        __syncthreads();
        if (threadIdx.x < 8) {
            float s = red[0][threadIdx.x] + red[1][threadIdx.x] + red[2][threadIdx.x] + red[3][threadIdx.x];
            atomicAdd(&attr_sum[threadIdx.x], s);
        }
    }
}

// ---------------- scan1: block-local exclusive scan + loop16 (block 0) ----------------
__global__ void k_scan1(const int* __restrict__ cnt, int* __restrict__ off,
                        int* __restrict__ bsum, int N,
                        const float* __restrict__ attr_sum, const float* __restrict__ We,
                        _Float16* __restrict__ loop16, float invE) {
    __shared__ int wpre[16];
    int i = blockIdx.x * 1024 + threadIdx.x;
    int lane = threadIdx.x & 63, wid = threadIdx.x >> 6;
    int v = (i < N) ? cnt[i] : 0;
    int s = v;
    #pragma unroll
    for (int d = 1; d < 64; d <<= 1) {
        int t = __shfl_up(s, d);
        if (lane >= d) s += t;
    }
    if (lane == 63) wpre[wid] = s;
    __syncthreads();
    if (threadIdx.x == 0) {
        int run = 0;
        #pragma unroll
        for (int q = 0; q < 16; ++q) { int t = wpre[q]; wpre[q] = run; run += t; }
        bsum[blockIdx.x] = run;
    }
    __syncthreads();
    if (i <= N) off[i] = wpre[wid] + s - v;  // exclusive within block (i==N: sentinel)

    if (blockIdx.x == 0 && threadIdx.x < HC) {
        int j = threadIdx.x;
        float acc = 0.f;
        #pragma unroll
        for (int d = 0; d < EDIM; ++d) acc += attr_sum[d] * invE * We[d * HC + j];
        loop16[j] = (_Float16)acc;
    }
}

// ---------------- scatter: CSR permute (no atomics), local block-prefix from bsum ----------------
__global__ void k_scatter(const int* __restrict__ ei, const float* __restrict__ ea,
                          const int* __restrict__ off, const int* __restrict__ bsum,
                          const int* __restrict__ rank,
                          int* __restrict__ esrc, h8* __restrict__ eac, int E, int nb) {
    int lane = threadIdx.x & 63;
    // local exclusive scan of bsum (nb <= 64)
    int bv = (lane < nb) ? bsum[lane] : 0;
    int s = bv;
    #pragma unroll
    for (int d = 1; d < 64; d <<= 1) {
        int t = __shfl_up(s, d);
        if (lane >= d) s += t;
    }
    s -= bv;  // exclusive

    int t = blockIdx.x * blockDim.x + threadIdx.x;
    if (t >= E) return;
    int dst = ei[E + t];
    int pos = off[dst] + __shfl(s, dst >> 10) + rank[t];
    esrc[pos] = ei[t];
    float4 a0 = *(const float4*)(ea + (size_t)t * EDIM);
    float4 a1 = *(const float4*)(ea + (size_t)t * EDIM + 4);
    h8 v;
    v[0] = (_Float16)a0.x; v[1] = (_Float16)a0.y; v[2] = (_Float16)a0.z; v[3] = (_Float16)a0.w;
    v[4] = (_Float16)a1.x; v[5] = (_Float16)a1.y; v[6] = (_Float16)a1.z; v[7] = (_Float16)a1.w;
    eac[pos] = v;
}

// ---------------- gather: wave per 2 dsts; 8 ch/lane, 4 edges/stage ----------------
__global__ __launch_bounds__(256) void k_gather(
        const int* __restrict__ esrc, const h8* __restrict__ eac,
        const _Float16* __restrict__ We16, const _Float16* __restrict__ att16,
        const _Float16* __restrict__ xh, const _Float16* __restrict__ loop16,
        const float* __restrict__ bias,
        const int* __restrict__ off, const int* __restrict__ bsum,
        float* __restrict__ out, int N, int nb) {
    int wid = (blockIdx.x * blockDim.x + threadIdx.x) >> 6;
    int lane = threadIdx.x & 63;
    int dst0 = wid * 2;
    if (dst0 >= N) return;
    int qid = lane >> 4;        // quarter owns one edge of each group of 4
    int l   = lane & 15;
    int c0  = l * 8;            // 8 channels/lane; head = l>>1 (lane pair)

    // local exclusive scan of bsum (nb <= 64)
    int bv = (lane < nb) ? bsum[lane] : 0;
    int sx = bv;
    #pragma unroll
    for (int d = 1; d < 64; d <<= 1) {
        int t = __shfl_up(sx, d);
        if (lane >= d) sx += t;
    }
    sx -= bv;  // exclusive

    // wave-invariant params
    h8 we8[EDIM];
    #pragma unroll
    for (int d = 0; d < EDIM; ++d) we8[d] = *(const h8*)(We16 + d * HC + c0);
    h8 av8 = *(const h8*)(att16 + c0);
    h2 att2[4];
    #pragma unroll
    for (int k = 0; k < 4; ++k) { att2[k][0] = av8[2 * k]; att2[k][1] = av8[2 * k + 1]; }
    h8 lp8 = *(const h8*)(loop16 + c0);
    const h8 z8 = {};
    h8 ng8;
    #pragma unroll
    for (int k = 0; k < 8; ++k) ng8[k] = (_Float16)NEG;

    for (int rep = 0; rep < 2; ++rep) {
        int dst = dst0 + rep;
        if (dst >= N) break;
        dst = __builtin_amdgcn_readfirstlane(dst);

        h8 xr8 = *(const h8*)(xh + (size_t)dst * 256 + HC + c0);

        float accv[8] = {0.f, 0.f, 0.f, 0.f, 0.f, 0.f, 0.f, 0.f};
        float segw = 0.f;

        auto TAIL = [&](h8 m8, h8 x8, bool valid) {
            h8 mp = __builtin_elementwise_max(m8, z8);
            h8 mn = __builtin_elementwise_min(m8, z8);
            m8 = mp + mn * ng8;
            float p = 0.f;
            #pragma unroll
            for (int k = 0; k < 4; ++k) {
                h2 mm; mm[0] = m8[2 * k]; mm[1] = m8[2 * k + 1];
                p = dot2(mm, att2[k], p);
            }
            p += __shfl_xor(p, 1);          // head logit (lane pair within quarter)
            float w = valid ? __expf(p) : 0.f;
            segw += w;
            #pragma unroll
            for (int k = 0; k < 8; ++k) accv[k] += w * (float)x8[k];
        };

        // self-loop (emb = loop16), counted once via qid==0
        {
            h8 x8 = *(const h8*)(xh + (size_t)dst * 256 + c0);
            TAIL(x8 + xr8 + lp8, x8, qid == 0);
        }

        int q0 = dst >> 10, q1 = (dst + 1) >> 10;
        int beg = off[dst] + __shfl(sx, q0);
        int end = off[dst + 1] + __shfl(sx, q1);
        if (beg < end) {
            int last = end - 1;
            int j = beg + qid; if (j > last) j = last;
            int s0 = esrc[j];
            h8 a0 = eac[j];
            h8 x0 = *(const h8*)(xh + (size_t)s0 * 256 + c0);
            for (int i = beg; i < end; i += 4) {
                int jn = i + 4 + qid; if (jn > last) jn = last;
                int sn = esrc[jn];
                h8 an = eac[jn];
                h8 xn = *(const h8*)(xh + (size_t)sn * 256 + c0);
                // compute with a0/x0 while next loads are in flight
                h8 m8 = x0 + xr8;
                #pragma unroll
                for (int d = 0; d < EDIM; ++d) {
                    h8 ad = {a0[d], a0[d], a0[d], a0[d], a0[d], a0[d], a0[d], a0[d]};
                    m8 += ad * we8[d];
                }
                TAIL(m8, x0, (i + qid) < end);
                a0 = an; x0 = xn;
            }
        }

        // combine quarters
        segw += __shfl_xor(segw, 16); segw += __shfl_xor(segw, 32);
        #pragma unroll
        for (int k = 0; k < 8; ++k) {
            accv[k] += __shfl_xor(accv[k], 16);
            accv[k] += __shfl_xor(accv[k], 32);
        }

        if (qid == 0) {
            float inv = 1.f / (segw + 1e-16f);
            f4 b0 = *(const f4*)(bias + c0), b1 = *(const f4*)(bias + c0 + 4);
            f4 o0, o1;
            o0[0] = accv[0] * inv + b0[0]; o0[1] = accv[1] * inv + b0[1];
            o0[2] = accv[2] * inv + b0[2]; o0[3] = accv[3] * inv + b0[3];
            o1[0] = accv[4] * inv + b1[0]; o1[1] = accv[5] * inv + b1[1];
            o1[2] = accv[6] * inv + b1[2]; o1[3] = accv[7] * inv + b1[3];
            *(f4*)(out + (size_t)dst * HC + c0)     = o0;
            *(f4*)(out + (size_t)dst * HC + c0 + 4) = o1;
        }
    }
}

extern "C" void kernel_launch(void* const* d_in, const int* in_sizes, int n_in,
                              void* d_out, int out_size, void* d_ws, size_t ws_size,
                              hipStream_t stream) {
    int N = in_sizes[0] / INC;
    int E = in_sizes[1] / 2;
    const float* x    = (const float*)d_in[0];
    const int*   ei   = (const int*)d_in[1];
    const float* ea   = (const float*)d_in[2];
    const float* Wl   = (const float*)d_in[3];
    const float* bl   = (const float*)d_in[4];
    const float* Wr   = (const float*)d_in[5];
    const float* br   = (const float*)d_in[6];
    const float* We   = (const float*)d_in[7];
    const float* att  = (const float*)d_in[8];
    const float* bias = (const float*)d_in[9];
    float* out = (float*)d_out;

    // workspace layout (16B-aligned blocks first)
    _Float16* xh      = (_Float16*)d_ws;                   // N*256 halfs
    h8*       eac     = (h8*)(xh + (size_t)N * 256);       // E * 16B
    float* attr_sum   = (float*)(eac + E);                 // 8
    int*   cnt        = (int*)(attr_sum + 8);              // N
    _Float16* loop16  = (_Float16*)(cnt + N);              // 128
    _Float16* packed  = loop16 + 128;                      // 32768 halfs
    _Float16* We16    = packed + 32768;                    // 1024 halfs
    _Float16* att16   = We16 + 1024;                       // 128 halfs
    int*   off        = (int*)(att16 + 128);               // N+2
    int*   rank       = off + (N + 2);                     // E
    int*   esrc       = rank + E;                          // E
    int*   bsum       = esrc + E;                          // 64

    // one memset covers attr_sum + cnt (contiguous)
    hipMemsetAsync(attr_sum, 0, (8 + (size_t)N) * sizeof(float), stream);

    k_packW<<<16, 256, 0, stream>>>(Wl, Wr, We, att, packed, We16, att16);

    int gemmBlocks = (N + 63) / 64;
    int histBlocks = (E + 255) / 256;
    k_phase1<<<gemmBlocks + histBlocks, 256, 0, stream>>>(x, packed, bl, br, xh,
                                                          ei, ea, cnt, rank, attr_sum,
                                                          N, E, gemmBlocks);

    int nb = (N + 1 + 1023) / 1024;
    k_scan1<<<nb, 1024, 0, stream>>>(cnt, off, bsum, N, attr_sum, We, loop16, 1.0f / (float)E);

    k_scatter<<<histBlocks, 256, 0, stream>>>(ei, ea, off, bsum, rank, esrc, eac, E, nb);

    int waves = (N + 1) / 2;
    k_gather<<<(waves * 64 + 255) / 256, 256, 0, stream>>>(esrc, eac, We16, att16, xh, loop16,
                                                           bias, off, bsum, out, N, nb);
}

// Round 13
// 165.974 us; speedup vs baseline: 1.1081x; 1.0121x over previous
//
#include <hip/hip_runtime.h>

#define NHEAD 8
#define CH    16
#define HC    128   // NHEAD*CH
#define INC   128   // in channels
#define EDIM  8
#define NEG   0.2f

typedef _Float16 h8 __attribute__((ext_vector_type(8)));
typedef _Float16 h2 __attribute__((ext_vector_type(2)));
typedef float    f4 __attribute__((ext_vector_type(4)));

__device__ __forceinline__ float dot2(h2 a, h2 b, float c) {
#if __has_builtin(__builtin_amdgcn_fdot2)
    return __builtin_amdgcn_fdot2(a, b, c, false);
#else
    return c + (float)a[0] * (float)b[0] + (float)a[1] * (float)b[1];
#endif
}

// ---------------- K1: fused {packW + We16/att16} + {hist/rank + attr_sum} ----------------
__global__ __launch_bounds__(256) void k_histpack(
        const float* __restrict__ Wl, const float* __restrict__ Wr,
        const float* __restrict__ We, const float* __restrict__ att,
        _Float16* __restrict__ packed, _Float16* __restrict__ We16, _Float16* __restrict__ att16,
        const int* __restrict__ ei, const float* __restrict__ ea,
        int* __restrict__ cnt, int* __restrict__ rank, float* __restrict__ attr_sum,
        int E) {
    __shared__ float red[4][8];
    if ((int)blockIdx.x < 16) {
        // pack part: 4096 threads total
        int id = blockIdx.x * 256 + threadIdx.x;
        int l  = id & 63;
        int kb = (id >> 6) & 3;
        int t  = id >> 8;
        int col = t * 16 + (l & 15);
        const float* W = (col < HC) ? Wl : Wr;
        int c = col & 127;
        int kbase = kb * 32 + (l >> 4) * 8;
        _Float16* dst = packed + (size_t)id * 8;
        #pragma unroll
        for (int j = 0; j < 8; ++j) dst[j] = (_Float16)W[(size_t)(kbase + j) * HC + c];
        if (id < 1024) We16[id] = (_Float16)We[id];
        if (id < 128)  att16[id] = (_Float16)att[id];
    } else {
        int t = (blockIdx.x - 16) * 256 + threadIdx.x;
        float av[8] = {0.f, 0.f, 0.f, 0.f, 0.f, 0.f, 0.f, 0.f};
        if (t < E) {
            rank[t] = atomicAdd(&cnt[ei[E + t]], 1);
            float4 a0 = *(const float4*)(ea + (size_t)t * EDIM);
            float4 a1 = *(const float4*)(ea + (size_t)t * EDIM + 4);
            av[0] = a0.x; av[1] = a0.y; av[2] = a0.z; av[3] = a0.w;
            av[4] = a1.x; av[5] = a1.y; av[6] = a1.z; av[7] = a1.w;
        }
        #pragma unroll
        for (int m = 1; m < 64; m <<= 1) {
            #pragma unroll
            for (int k = 0; k < 8; ++k) av[k] += __shfl_xor(av[k], m);
        }
        int lane = threadIdx.x & 63, wid = threadIdx.x >> 6;
        if (lane == 0) {
            #pragma unroll
            for (int k = 0; k < 8; ++k) red[wid][k] = av[k];
        }
        __syncthreads();
        if (threadIdx.x < 8) {
            float s = red[0][threadIdx.x] + red[1][threadIdx.x] + red[2][threadIdx.x] + red[3][threadIdx.x];
            atomicAdd(&attr_sum[threadIdx.x], s);
        }
    }
}

// ---------------- K2: block-local exclusive scan + loop16 (block 0) ----------------
__global__ void k_scan1(const int* __restrict__ cnt, int* __restrict__ off,
                        int* __restrict__ bsum, int N,
                        const float* __restrict__ attr_sum, const float* __restrict__ We,
                        _Float16* __restrict__ loop16, float invE) {
    __shared__ int wpre[16];
    int i = blockIdx.x * 1024 + threadIdx.x;
    int lane = threadIdx.x & 63, wid = threadIdx.x >> 6;
    int v = (i < N) ? cnt[i] : 0;
    int s = v;
    #pragma unroll
    for (int d = 1; d < 64; d <<= 1) {
        int t = __shfl_up(s, d);
        if (lane >= d) s += t;
    }
    if (lane == 63) wpre[wid] = s;
    __syncthreads();
    if (threadIdx.x == 0) {
        int run = 0;
        #pragma unroll
        for (int q = 0; q < 16; ++q) { int t = wpre[q]; wpre[q] = run; run += t; }
        bsum[blockIdx.x] = run;
    }
    __syncthreads();
    if (i <= N) off[i] = wpre[wid] + s - v;  // exclusive within block (i==N: sentinel)

    if (blockIdx.x == 0 && threadIdx.x < HC) {
        int j = threadIdx.x;
        float acc = 0.f;
        #pragma unroll
        for (int d = 0; d < EDIM; ++d) acc += attr_sum[d] * invE * We[d * HC + j];
        loop16[j] = (_Float16)acc;
    }
}

// ---------------- K3: fused {MFMA dual GEMM, 64 nodes/block} || {scatter permute} ----------------
__global__ __launch_bounds__(256) void k_phase2(
        const float* __restrict__ x, const _Float16* __restrict__ packed,
        const float* __restrict__ bl, const float* __restrict__ br,
        _Float16* __restrict__ xh,
        const int* __restrict__ ei, const float* __restrict__ ea,
        const int* __restrict__ off, const int* __restrict__ bsum,
        const int* __restrict__ rank,
        int* __restrict__ esrc, h8* __restrict__ eac,
        int N, int E, int gemmBlocks, int nb) {
    __shared__ _Float16 st[16][264];

    if ((int)blockIdx.x < gemmBlocks) {
        int nb0 = blockIdx.x * 64;
        int w  = threadIdx.x >> 6;
        int l  = threadIdx.x & 63;

        const h8* pk = (const h8*)packed;
        h8 bfrag[4][4];
        #pragma unroll
        for (int t4 = 0; t4 < 4; ++t4)
            #pragma unroll
            for (int kb = 0; kb < 4; ++kb)
                bfrag[t4][kb] = pk[(size_t)(((w * 4 + t4) * 4 + kb) * 64 + l)];

        float bv[4];
        int cl = l & 15;
        #pragma unroll
        for (int t4 = 0; t4 < 4; ++t4) {
            int col = w * 64 + t4 * 16 + cl;
            bv[t4] = (col < HC) ? bl[col] : br[col - HC];
        }

        int g = l >> 4;
        int r0 = g * 4;
        for (int mt = 0; mt < 4; ++mt) {
            int m0 = nb0 + mt * 16;
            if (m0 >= N) break;
            int row = m0 + cl; if (row >= N) row = N - 1;
            const float* xp = x + (size_t)row * INC + g * 8;
            h8 afrag[4];
            #pragma unroll
            for (int kb = 0; kb < 4; ++kb) {
                float4 u = *(const float4*)(xp + kb * 32);
                float4 v = *(const float4*)(xp + kb * 32 + 4);
                h8 a;
                a[0] = (_Float16)u.x; a[1] = (_Float16)u.y; a[2] = (_Float16)u.z; a[3] = (_Float16)u.w;
                a[4] = (_Float16)v.x; a[5] = (_Float16)v.y; a[6] = (_Float16)v.z; a[7] = (_Float16)v.w;
                afrag[kb] = a;
            }
            f4 acc[4];
            #pragma unroll
            for (int t4 = 0; t4 < 4; ++t4) { f4 z = {0.f, 0.f, 0.f, 0.f}; acc[t4] = z; }
            #pragma unroll
            for (int kb = 0; kb < 4; ++kb)
                #pragma unroll
                for (int t4 = 0; t4 < 4; ++t4)
                    acc[t4] = __builtin_amdgcn_mfma_f32_16x16x32_f16(afrag[kb], bfrag[t4][kb], acc[t4], 0, 0, 0);
            #pragma unroll
            for (int t4 = 0; t4 < 4; ++t4) {
                int col = w * 64 + t4 * 16 + cl;
                #pragma unroll
                for (int j = 0; j < 4; ++j)
                    st[r0 + j][col] = (_Float16)(acc[t4][j] + bv[t4]);
            }
            __syncthreads();
            #pragma unroll
            for (int q = 0; q < 2; ++q) {
                int cch = threadIdx.x + 256 * q;
                int r = cch >> 5, ch = (cch & 31) * 8;
                int node = m0 + r;
                if (node < N) *(h8*)(xh + (size_t)node * 256 + ch) = *(const h8*)&st[r][ch];
            }
            __syncthreads();
        }
    } else {
        int lane = threadIdx.x & 63;
        // local exclusive scan of bsum (nb <= 64)
        int bv = (lane < nb) ? bsum[lane] : 0;
        int s = bv;
        #pragma unroll
        for (int d = 1; d < 64; d <<= 1) {
            int t = __shfl_up(s, d);
            if (lane >= d) s += t;
        }
        s -= bv;  // exclusive

        int t = (blockIdx.x - gemmBlocks) * 256 + threadIdx.x;
        if (t >= E) return;
        int dst = ei[E + t];
        int pos = off[dst] + __shfl(s, dst >> 10) + rank[t];
        esrc[pos] = ei[t];
        float4 a0 = *(const float4*)(ea + (size_t)t * EDIM);
        float4 a1 = *(const float4*)(ea + (size_t)t * EDIM + 4);
        h8 v;
        v[0] = (_Float16)a0.x; v[1] = (_Float16)a0.y; v[2] = (_Float16)a0.z; v[3] = (_Float16)a0.w;
        v[4] = (_Float16)a1.x; v[5] = (_Float16)a1.y; v[6] = (_Float16)a1.z; v[7] = (_Float16)a1.w;
        eac[pos] = v;
    }
}

// ---------------- K4: gather, wave per dst; 8 ch/lane, 4 edges/stage ----------------
__global__ __launch_bounds__(256) void k_gather(
        const int* __restrict__ esrc, const h8* __restrict__ eac,
        const _Float16* __restrict__ We16, const _Float16* __restrict__ att16,
        const _Float16* __restrict__ xh, const _Float16* __restrict__ loop16,
        const float* __restrict__ bias,
        const int* __restrict__ off, const int* __restrict__ bsum,
        float* __restrict__ out, int N, int nb) {
    int wave = (blockIdx.x * blockDim.x + threadIdx.x) >> 6;
    int lane = threadIdx.x & 63;
    if (wave >= N) return;
    int dst = __builtin_amdgcn_readfirstlane(wave);
    int qid = lane >> 4;        // quarter owns one edge of each group of 4
    int l   = lane & 15;
    int c0  = l * 8;            // 8 channels/lane; head = l>>1 (lane pair)

    // local exclusive scan of bsum (nb <= 64)
    int bv = (lane < nb) ? bsum[lane] : 0;
    int sx = bv;
    #pragma unroll
    for (int d = 1; d < 64; d <<= 1) {
        int t = __shfl_up(sx, d);
        if (lane >= d) sx += t;
    }
    sx -= bv;  // exclusive

    // wave-invariant params
    h8 we8[EDIM];
    #pragma unroll
    for (int d = 0; d < EDIM; ++d) we8[d] = *(const h8*)(We16 + d * HC + c0);
    h8 av8 = *(const h8*)(att16 + c0);
    h2 att2[4];
    #pragma unroll
    for (int k = 0; k < 4; ++k) { att2[k][0] = av8[2 * k]; att2[k][1] = av8[2 * k + 1]; }
    h8 lp8 = *(const h8*)(loop16 + c0);
    const h8 z8 = {};
    h8 ng8;
    #pragma unroll
    for (int k = 0; k < 8; ++k) ng8[k] = (_Float16)NEG;

    h8 xr8 = *(const h8*)(xh + (size_t)dst * 256 + HC + c0);

    float accv[8] = {0.f, 0.f, 0.f, 0.f, 0.f, 0.f, 0.f, 0.f};
    float segw = 0.f;

    auto TAIL = [&](h8 m8, h8 x8, bool valid) {
        h8 mp = __builtin_elementwise_max(m8, z8);
        h8 mn = __builtin_elementwise_min(m8, z8);
        m8 = mp + mn * ng8;
        float p = 0.f;
        #pragma unroll
        for (int k = 0; k < 4; ++k) {
            h2 mm; mm[0] = m8[2 * k]; mm[1] = m8[2 * k + 1];
            p = dot2(mm, att2[k], p);
        }
        p += __shfl_xor(p, 1);          // head logit (lane pair within quarter)
        float w = valid ? __expf(p) : 0.f;
        segw += w;
        #pragma unroll
        for (int k = 0; k < 8; ++k) accv[k] += w * (float)x8[k];
    };

    // self-loop (emb = loop16), counted once via qid==0
    {
        h8 x8 = *(const h8*)(xh + (size_t)dst * 256 + c0);
        TAIL(x8 + xr8 + lp8, x8, qid == 0);
    }

    int q0 = dst >> 10, q1 = (dst + 1) >> 10;
    int beg = off[dst] + __shfl(sx, q0);
    int end = off[dst + 1] + __shfl(sx, q1);
    if (beg < end) {
        int last = end - 1;
        int j = beg + qid; if (j > last) j = last;
        int s0 = esrc[j];
        h8 a0 = eac[j];
        h8 x0 = *(const h8*)(xh + (size_t)s0 * 256 + c0);
        for (int i = beg; i < end; i += 4) {
            int jn = i + 4 + qid; if (jn > last) jn = last;
            int sn = esrc[jn];
            h8 an = eac[jn];
            h8 xn = *(const h8*)(xh + (size_t)sn * 256 + c0);
            // compute with a0/x0 while next loads are in flight
            h8 m8 = x0 + xr8;
            #pragma unroll
            for (int d = 0; d < EDIM; ++d) {
                h8 ad = {a0[d], a0[d], a0[d], a0[d], a0[d], a0[d], a0[d], a0[d]};
                m8 += ad * we8[d];
            }
            TAIL(m8, x0, (i + qid) < end);
            a0 = an; x0 = xn;
        }
    }

    // combine quarters
    segw += __shfl_xor(segw, 16); segw += __shfl_xor(segw, 32);
    #pragma unroll
    for (int k = 0; k < 8; ++k) {
        accv[k] += __shfl_xor(accv[k], 16);
        accv[k] += __shfl_xor(accv[k], 32);
    }

    if (qid == 0) {
        float inv = 1.f / (segw + 1e-16f);
        f4 b0 = *(const f4*)(bias + c0), b1 = *(const f4*)(bias + c0 + 4);
        f4 o0, o1;
        o0[0] = accv[0] * inv + b0[0]; o0[1] = accv[1] * inv + b0[1];
        o0[2] = accv[2] * inv + b0[2]; o0[3] = accv[3] * inv + b0[3];
        o1[0] = accv[4] * inv + b1[0]; o1[1] = accv[5] * inv + b1[1];
        o1[2] = accv[6] * inv + b1[2]; o1[3] = accv[7] * inv + b1[3];
        *(f4*)(out + (size_t)dst * HC + c0)     = o0;
        *(f4*)(out + (size_t)dst * HC + c0 + 4) = o1;
    }
}

extern "C" void kernel_launch(void* const* d_in, const int* in_sizes, int n_in,
                              void* d_out, int out_size, void* d_ws, size_t ws_size,
                              hipStream_t stream) {
    int N = in_sizes[0] / INC;
    int E = in_sizes[1] / 2;
    const float* x    = (const float*)d_in[0];
    const int*   ei   = (const int*)d_in[1];
    const float* ea   = (const float*)d_in[2];
    const float* Wl   = (const float*)d_in[3];
    const float* bl   = (const float*)d_in[4];
    const float* Wr   = (const float*)d_in[5];
    const float* br   = (const float*)d_in[6];
    const float* We   = (const float*)d_in[7];
    const float* att  = (const float*)d_in[8];
    const float* bias = (const float*)d_in[9];
    float* out = (float*)d_out;

    // workspace layout (16B-aligned blocks first)
    _Float16* xh      = (_Float16*)d_ws;                   // N*256 halfs
    h8*       eac     = (h8*)(xh + (size_t)N * 256);       // E * 16B
    float* attr_sum   = (float*)(eac + E);                 // 8
    int*   cnt        = (int*)(attr_sum + 8);              // N
    _Float16* loop16  = (_Float16*)(cnt + N);              // 128
    _Float16* packed  = loop16 + 128;                      // 32768 halfs
    _Float16* We16    = packed + 32768;                    // 1024 halfs
    _Float16* att16   = We16 + 1024;                       // 128 halfs
    int*   off        = (int*)(att16 + 128);               // N+2
    int*   rank       = off + (N + 2);                     // E
    int*   esrc       = rank + E;                          // E
    int*   bsum       = esrc + E;                          // 64

    // one memset covers attr_sum + cnt (contiguous)
    hipMemsetAsync(attr_sum, 0, (8 + (size_t)N) * sizeof(float), stream);

    int histBlocks = (E + 255) / 256;
    k_histpack<<<16 + histBlocks, 256, 0, stream>>>(Wl, Wr, We, att, packed, We16, att16,
                                                    ei, ea, cnt, rank, attr_sum, E);

    int nb = (N + 1 + 1023) / 1024;
    k_scan1<<<nb, 1024, 0, stream>>>(cnt, off, bsum, N, attr_sum, We, loop16, 1.0f / (float)E);

    int gemmBlocks = (N + 63) / 64;
    k_phase2<<<gemmBlocks + histBlocks, 256, 0, stream>>>(x, packed, bl, br, xh,
                                                          ei, ea, off, bsum, rank,
                                                          esrc, eac, N, E, gemmBlocks, nb);

    k_gather<<<((size_t)N * 64 + 255) / 256, 256, 0, stream>>>(esrc, eac, We16, att16, xh, loop16,
                                                               bias, off, bsum, out, N, nb);
}

// Round 14
// 163.016 us; speedup vs baseline: 1.1282x; 1.0181x over previous
//
#include <hip/hip_runtime.h>

#define NHEAD 8
#define CH    16
#define HC    128   // NHEAD*CH
#define INC   128   // in channels
#define EDIM  8
#define NEG   0.2f

typedef _Float16 h8 __attribute__((ext_vector_type(8)));
typedef _Float16 h2 __attribute__((ext_vector_type(2)));
typedef float    f4 __attribute__((ext_vector_type(4)));

__device__ __forceinline__ float dot2(h2 a, h2 b, float c) {
#if __has_builtin(__builtin_amdgcn_fdot2)
    return __builtin_amdgcn_fdot2(a, b, c, false);
#else
    return c + (float)a[0] * (float)b[0] + (float)a[1] * (float)b[1];
#endif
}

// ---------------- K1: fused {packW + We16/att16} + {hist/rank + attr_sum} ----------------
__global__ __launch_bounds__(256) void k_histpack(
        const float* __restrict__ Wl, const float* __restrict__ Wr,
        const float* __restrict__ We, const float* __restrict__ att,
        _Float16* __restrict__ packed, _Float16* __restrict__ We16, _Float16* __restrict__ att16,
        const int* __restrict__ ei, const float* __restrict__ ea,
        int* __restrict__ cnt, int* __restrict__ rank, float* __restrict__ attr_sum,
        int E) {
    __shared__ float red[4][8];
    if ((int)blockIdx.x < 16) {
        int id = blockIdx.x * 256 + threadIdx.x;
        int l  = id & 63;
        int kb = (id >> 6) & 3;
        int t  = id >> 8;
        int col = t * 16 + (l & 15);
        const float* W = (col < HC) ? Wl : Wr;
        int c = col & 127;
        int kbase = kb * 32 + (l >> 4) * 8;
        _Float16* dst = packed + (size_t)id * 8;
        #pragma unroll
        for (int j = 0; j < 8; ++j) dst[j] = (_Float16)W[(size_t)(kbase + j) * HC + c];
        if (id < 1024) We16[id] = (_Float16)We[id];
        if (id < 128)  att16[id] = (_Float16)att[id];
    } else {
        int t = (blockIdx.x - 16) * 256 + threadIdx.x;
        float av[8] = {0.f, 0.f, 0.f, 0.f, 0.f, 0.f, 0.f, 0.f};
        if (t < E) {
            rank[t] = atomicAdd(&cnt[ei[E + t]], 1);
            float4 a0 = *(const float4*)(ea + (size_t)t * EDIM);
            float4 a1 = *(const float4*)(ea + (size_t)t * EDIM + 4);
            av[0] = a0.x; av[1] = a0.y; av[2] = a0.z; av[3] = a0.w;
            av[4] = a1.x; av[5] = a1.y; av[6] = a1.z; av[7] = a1.w;
        }
        #pragma unroll
        for (int m = 1; m < 64; m <<= 1) {
            #pragma unroll
            for (int k = 0; k < 8; ++k) av[k] += __shfl_xor(av[k], m);
        }
        int lane = threadIdx.x & 63, wid = threadIdx.x >> 6;
        if (lane == 0) {
            #pragma unroll
            for (int k = 0; k < 8; ++k) red[wid][k] = av[k];
        }
        __syncthreads();
        if (threadIdx.x < 8) {
            float s = red[0][threadIdx.x] + red[1][threadIdx.x] + red[2][threadIdx.x] + red[3][threadIdx.x];
            atomicAdd(&attr_sum[threadIdx.x], s);
        }
    }
}

// ---------------- K2: block-local exclusive scan + loop16 (block 0) ----------------
__global__ void k_scan1(const int* __restrict__ cnt, int* __restrict__ off,
                        int* __restrict__ bsum, int N,
                        const float* __restrict__ attr_sum, const float* __restrict__ We,
                        _Float16* __restrict__ loop16, float invE) {
    __shared__ int wpre[16];
    int i = blockIdx.x * 1024 + threadIdx.x;
    int lane = threadIdx.x & 63, wid = threadIdx.x >> 6;
    int v = (i < N) ? cnt[i] : 0;
    int s = v;
    #pragma unroll
    for (int d = 1; d < 64; d <<= 1) {
        int t = __shfl_up(s, d);
        if (lane >= d) s += t;
    }
    if (lane == 63) wpre[wid] = s;
    __syncthreads();
    if (threadIdx.x == 0) {
        int run = 0;
        #pragma unroll
        for (int q = 0; q < 16; ++q) { int t = wpre[q]; wpre[q] = run; run += t; }
        bsum[blockIdx.x] = run;
    }
    __syncthreads();
    if (i <= N) off[i] = wpre[wid] + s - v;  // exclusive within block (i==N: sentinel)

    if (blockIdx.x == 0 && threadIdx.x < HC) {
        int j = threadIdx.x;
        float acc = 0.f;
        #pragma unroll
        for (int d = 0; d < EDIM; ++d) acc += attr_sum[d] * invE * We[d * HC + j];
        loop16[j] = (_Float16)acc;
    }
}

// ---------------- K3: fused {MFMA dual GEMM, 64 nodes/block} || {scatter permute} ----------------
__global__ __launch_bounds__(256) void k_phase2(
        const float* __restrict__ x, const _Float16* __restrict__ packed,
        const float* __restrict__ bl, const float* __restrict__ br,
        _Float16* __restrict__ xh,
        const int* __restrict__ ei, const float* __restrict__ ea,
        const int* __restrict__ off, const int* __restrict__ bsum,
        const int* __restrict__ rank,
        int* __restrict__ esrc, h8* __restrict__ eac,
        int N, int E, int gemmBlocks, int nb) {
    __shared__ _Float16 st[16][264];

    if ((int)blockIdx.x < gemmBlocks) {
        int nb0 = blockIdx.x * 64;
        int w  = threadIdx.x >> 6;
        int l  = threadIdx.x & 63;

        const h8* pk = (const h8*)packed;
        h8 bfrag[4][4];
        #pragma unroll
        for (int t4 = 0; t4 < 4; ++t4)
            #pragma unroll
            for (int kb = 0; kb < 4; ++kb)
                bfrag[t4][kb] = pk[(size_t)(((w * 4 + t4) * 4 + kb) * 64 + l)];

        float bv[4];
        int cl = l & 15;
        #pragma unroll
        for (int t4 = 0; t4 < 4; ++t4) {
            int col = w * 64 + t4 * 16 + cl;
            bv[t4] = (col < HC) ? bl[col] : br[col - HC];
        }

        int g = l >> 4;
        int r0 = g * 4;
        for (int mt = 0; mt < 4; ++mt) {
            int m0 = nb0 + mt * 16;
            if (m0 >= N) break;
            int row = m0 + cl; if (row >= N) row = N - 1;
            const float* xp = x + (size_t)row * INC + g * 8;
            h8 afrag[4];
            #pragma unroll
            for (int kb = 0; kb < 4; ++kb) {
                float4 u = *(const float4*)(xp + kb * 32);
                float4 v = *(const float4*)(xp + kb * 32 + 4);
                h8 a;
                a[0] = (_Float16)u.x; a[1] = (_Float16)u.y; a[2] = (_Float16)u.z; a[3] = (_Float16)u.w;
                a[4] = (_Float16)v.x; a[5] = (_Float16)v.y; a[6] = (_Float16)v.z; a[7] = (_Float16)v.w;
                afrag[kb] = a;
            }
            f4 acc[4];
            #pragma unroll
            for (int t4 = 0; t4 < 4; ++t4) { f4 z = {0.f, 0.f, 0.f, 0.f}; acc[t4] = z; }
            #pragma unroll
            for (int kb = 0; kb < 4; ++kb)
                #pragma unroll
                for (int t4 = 0; t4 < 4; ++t4)
                    acc[t4] = __builtin_amdgcn_mfma_f32_16x16x32_f16(afrag[kb], bfrag[t4][kb], acc[t4], 0, 0, 0);
            #pragma unroll
            for (int t4 = 0; t4 < 4; ++t4) {
                int col = w * 64 + t4 * 16 + cl;
                #pragma unroll
                for (int j = 0; j < 4; ++j)
                    st[r0 + j][col] = (_Float16)(acc[t4][j] + bv[t4]);
            }
            __syncthreads();
            #pragma unroll
            for (int q = 0; q < 2; ++q) {
                int cch = threadIdx.x + 256 * q;
                int r = cch >> 5, ch = (cch & 31) * 8;
                int node = m0 + r;
                if (node < N) *(h8*)(xh + (size_t)node * 256 + ch) = *(const h8*)&st[r][ch];
            }
            __syncthreads();
        }
    } else {
        int lane = threadIdx.x & 63;
        int bv = (lane < nb) ? bsum[lane] : 0;
        int s = bv;
        #pragma unroll
        for (int d = 1; d < 64; d <<= 1) {
            int t = __shfl_up(s, d);
            if (lane >= d) s += t;
        }
        s -= bv;  // exclusive

        int t = (blockIdx.x - gemmBlocks) * 256 + threadIdx.x;
        if (t >= E) return;
        int dst = ei[E + t];
        int pos = off[dst] + __shfl(s, dst >> 10) + rank[t];
        esrc[pos] = ei[t];
        float4 a0 = *(const float4*)(ea + (size_t)t * EDIM);
        float4 a1 = *(const float4*)(ea + (size_t)t * EDIM + 4);
        h8 v;
        v[0] = (_Float16)a0.x; v[1] = (_Float16)a0.y; v[2] = (_Float16)a0.z; v[3] = (_Float16)a0.w;
        v[4] = (_Float16)a1.x; v[5] = (_Float16)a1.y; v[6] = (_Float16)a1.z; v[7] = (_Float16)a1.w;
        eac[pos] = v;
    }
}

// ---------------- K4: gather, wave per TWO dsts interleaved; 8 ch/lane, 4 edges/stage each ----------------
__global__ __launch_bounds__(256) void k_gather(
        const int* __restrict__ esrc, const h8* __restrict__ eac,
        const _Float16* __restrict__ We16, const _Float16* __restrict__ att16,
        const _Float16* __restrict__ xh, const _Float16* __restrict__ loop16,
        const float* __restrict__ bias,
        const int* __restrict__ off, const int* __restrict__ bsum,
        float* __restrict__ out, int N, int nb) {
    int wid = (blockIdx.x * blockDim.x + threadIdx.x) >> 6;
    int lane = threadIdx.x & 63;
    int dstA = wid * 2;
    if (dstA >= N) return;
    dstA = __builtin_amdgcn_readfirstlane(dstA);
    bool hasB = (dstA + 1) < N;
    int dstB = hasB ? dstA + 1 : dstA;   // clamped for loads

    int qid = lane >> 4;        // quarter owns one edge of each group of 4
    int l   = lane & 15;
    int c0  = l * 8;            // 8 channels/lane; head = l>>1 (lane pair)

    // local exclusive scan of bsum (nb <= 64)
    int bv = (lane < nb) ? bsum[lane] : 0;
    int sx = bv;
    #pragma unroll
    for (int d = 1; d < 64; d <<= 1) {
        int t = __shfl_up(sx, d);
        if (lane >= d) sx += t;
    }
    sx -= bv;  // exclusive

    // wave-invariant params
    h8 we8[EDIM];
    #pragma unroll
    for (int d = 0; d < EDIM; ++d) we8[d] = *(const h8*)(We16 + d * HC + c0);
    h8 av8 = *(const h8*)(att16 + c0);
    h2 att2[4];
    #pragma unroll
    for (int k = 0; k < 4; ++k) { att2[k][0] = av8[2 * k]; att2[k][1] = av8[2 * k + 1]; }
    h8 lp8 = *(const h8*)(loop16 + c0);
    const h8 z8 = {};
    h8 ng8;
    #pragma unroll
    for (int k = 0; k < 8; ++k) ng8[k] = (_Float16)NEG;

    h8 xrA = *(const h8*)(xh + (size_t)dstA * 256 + HC + c0);
    h8 xrB = *(const h8*)(xh + (size_t)dstB * 256 + HC + c0);

    float accA[8] = {0.f, 0.f, 0.f, 0.f, 0.f, 0.f, 0.f, 0.f};
    float accB[8] = {0.f, 0.f, 0.f, 0.f, 0.f, 0.f, 0.f, 0.f};
    float segA = 0.f, segB = 0.f;

    auto TAIL = [&](h8 m8, h8 x8, bool valid, float (&av)[8], float &sw) {
        h8 mp = __builtin_elementwise_max(m8, z8);
        h8 mn = __builtin_elementwise_min(m8, z8);
        m8 = mp + mn * ng8;
        float p = 0.f;
        #pragma unroll
        for (int k = 0; k < 4; ++k) {
            h2 mm; mm[0] = m8[2 * k]; mm[1] = m8[2 * k + 1];
            p = dot2(mm, att2[k], p);
        }
        p += __shfl_xor(p, 1);          // head logit (lane pair within quarter)
        float w = valid ? __expf(p) : 0.f;
        sw += w;
        #pragma unroll
        for (int k = 0; k < 8; ++k) av[k] += w * (float)x8[k];
    };

    // self-loops (emb = loop16), counted once via qid==0
    {
        h8 x8 = *(const h8*)(xh + (size_t)dstA * 256 + c0);
        TAIL(x8 + xrA + lp8, x8, qid == 0, accA, segA);
    }
    {
        h8 x8 = *(const h8*)(xh + (size_t)dstB * 256 + c0);
        TAIL(x8 + xrB + lp8, x8, hasB && qid == 0, accB, segB);
    }

    int begA = off[dstA] + __shfl(sx, dstA >> 10);
    int endA = off[dstA + 1] + __shfl(sx, (dstA + 1) >> 10);
    int begB = begA, endB = begA;     // default: empty stream
    if (hasB) {
        begB = endA;                   // adjacent CSR ranges
        endB = off[dstA + 2] + __shfl(sx, (dstA + 2) >> 10);
    }

    if (begA < endA || begB < endB) {
        int lastA = endA - 1, lastB = endB - 1;
        bool okA = endA > begA, okB = endB > begB;
        auto IDXA = [&](int i) { int j = i + qid; j = (j > lastA) ? lastA : j; return okA ? j : 0; };
        auto IDXB = [&](int i) { int j = i + qid; j = (j > lastB) ? lastB : j; return okB ? j : 0; };

        int jA = IDXA(begA), jB = IDXB(begB);
        int sA = esrc[jA]; h8 aA = eac[jA];
        int sB = esrc[jB]; h8 aB = eac[jB];
        h8 xA = *(const h8*)(xh + (size_t)sA * 256 + c0);
        h8 xB = *(const h8*)(xh + (size_t)sB * 256 + c0);

        int iA = begA, iB = begB;
        while (iA < endA || iB < endB) {
            // issue next-iteration loads for both streams (2x outstanding chains)
            int jnA = IDXA(iA + 4), jnB = IDXB(iB + 4);
            int snA = esrc[jnA]; h8 anA = eac[jnA];
            int snB = esrc[jnB]; h8 anB = eac[jnB];
            h8 xnA = *(const h8*)(xh + (size_t)snA * 256 + c0);
            h8 xnB = *(const h8*)(xh + (size_t)snB * 256 + c0);

            // compute stream A
            {
                h8 m8 = xA + xrA;
                #pragma unroll
                for (int d = 0; d < EDIM; ++d) {
                    h8 ad = {aA[d], aA[d], aA[d], aA[d], aA[d], aA[d], aA[d], aA[d]};
                    m8 += ad * we8[d];
                }
                TAIL(m8, xA, (iA + qid) < endA, accA, segA);
            }
            // compute stream B
            {
                h8 m8 = xB + xrB;
                #pragma unroll
                for (int d = 0; d < EDIM; ++d) {
                    h8 ad = {aB[d], aB[d], aB[d], aB[d], aB[d], aB[d], aB[d], aB[d]};
                    m8 += ad * we8[d];
                }
                TAIL(m8, xB, (iB + qid) < endB, accB, segB);
            }
            aA = anA; xA = xnA; aB = anB; xB = xnB;
            iA += 4; iB += 4;
        }
    }

    // combine quarters
    segA += __shfl_xor(segA, 16); segA += __shfl_xor(segA, 32);
    segB += __shfl_xor(segB, 16); segB += __shfl_xor(segB, 32);
    #pragma unroll
    for (int k = 0; k < 8; ++k) {
        accA[k] += __shfl_xor(accA[k], 16); accA[k] += __shfl_xor(accA[k], 32);
        accB[k] += __shfl_xor(accB[k], 16); accB[k] += __shfl_xor(accB[k], 32);
    }

    if (qid == 0) {
        f4 b0 = *(const f4*)(bias + c0), b1 = *(const f4*)(bias + c0 + 4);
        {
            float inv = 1.f / (segA + 1e-16f);
            f4 o0, o1;
            o0[0] = accA[0] * inv + b0[0]; o0[1] = accA[1] * inv + b0[1];
            o0[2] = accA[2] * inv + b0[2]; o0[3] = accA[3] * inv + b0[3];
            o1[0] = accA[4] * inv + b1[0]; o1[1] = accA[5] * inv + b1[1];
            o1[2] = accA[6] * inv + b1[2]; o1[3] = accA[7] * inv + b1[3];
            *(f4*)(out + (size_t)dstA * HC + c0)     = o0;
            *(f4*)(out + (size_t)dstA * HC + c0 + 4) = o1;
        }
        if (hasB) {
            float inv = 1.f / (segB + 1e-16f);
            f4 o0, o1;
            o0[0] = accB[0] * inv + b0[0]; o0[1] = accB[1] * inv + b0[1];
            o0[2] = accB[2] * inv + b0[2]; o0[3] = accB[3] * inv + b0[3];
            o1[0] = accB[4] * inv + b1[0]; o1[1] = accB[5] * inv + b1[1];
            o1[2] = accB[6] * inv + b1[2]; o1[3] = accB[7] * inv + b1[3];
            *(f4*)(out + (size_t)dstB * HC + c0)     = o0;
            *(f4*)(out + (size_t)dstB * HC + c0 + 4) = o1;
        }
    }
}

extern "C" void kernel_launch(void* const* d_in, const int* in_sizes, int n_in,
                              void* d_out, int out_size, void* d_ws, size_t ws_size,
                              hipStream_t stream) {
    int N = in_sizes[0] / INC;
    int E = in_sizes[1] / 2;
    const float* x    = (const float*)d_in[0];
    const int*   ei   = (const int*)d_in[1];
    const float* ea   = (const float*)d_in[2];
    const float* Wl   = (const float*)d_in[3];
    const float* bl   = (const float*)d_in[4];
    const float* Wr   = (const float*)d_in[5];
    const float* br   = (const float*)d_in[6];
    const float* We   = (const float*)d_in[7];
    const float* att  = (const float*)d_in[8];
    const float* bias = (const float*)d_in[9];
    float* out = (float*)d_out;

    // workspace layout (16B-aligned blocks first)
    _Float16* xh      = (_Float16*)d_ws;                   // N*256 halfs
    h8*       eac     = (h8*)(xh + (size_t)N * 256);       // E * 16B
    float* attr_sum   = (float*)(eac + E);                 // 8
    int*   cnt        = (int*)(attr_sum + 8);              // N
    _Float16* loop16  = (_Float16*)(cnt + N);              // 128
    _Float16* packed  = loop16 + 128;                      // 32768 halfs
    _Float16* We16    = packed + 32768;                    // 1024 halfs
    _Float16* att16   = We16 + 1024;                       // 128 halfs
    int*   off        = (int*)(att16 + 128);               // N+2
    int*   rank       = off + (N + 2);                     // E
    int*   esrc       = rank + E;                          // E
    int*   bsum       = esrc + E;                          // 64

    // one memset covers attr_sum + cnt (contiguous)
    hipMemsetAsync(attr_sum, 0, (8 + (size_t)N) * sizeof(float), stream);

    int histBlocks = (E + 255) / 256;
    k_histpack<<<16 + histBlocks, 256, 0, stream>>>(Wl, Wr, We, att, packed, We16, att16,
                                                    ei, ea, cnt, rank, attr_sum, E);

    int nb = (N + 1 + 1023) / 1024;
    k_scan1<<<nb, 1024, 0, stream>>>(cnt, off, bsum, N, attr_sum, We, loop16, 1.0f / (float)E);

    int gemmBlocks = (N + 63) / 64;
    k_phase2<<<gemmBlocks + histBlocks, 256, 0, stream>>>(x, packed, bl, br, xh,
                                                          ei, ea, off, bsum, rank,
                                                          esrc, eac, N, E, gemmBlocks, nb);

    int waves = (N + 1) / 2;
    k_gather<<<((size_t)waves * 64 + 255) / 256, 256, 0, stream>>>(esrc, eac, We16, att16, xh, loop16,
                                                                   bias, off, bsum, out, N, nb);
}